// Round 8
// baseline (210.267 us; speedup 1.0000x reference)
//
#include <hip/hip_runtime.h>
#include <math.h>

#define N_ROWS   512     // 8*16*4
#define NBINS    257
#define KPAD     576     // padded K per window-half (18*32)
#define NCHUNKB  36      // B K-chunks: 18 unshifted (h1) + 18 shifted (h2)
#define PCH      9       // A-chunks resident per phase
#define PCOLS    288     // A columns generated per phase
#define NOUT     256     // output samples per frame (STEP)
#define N_FRAMES 128
#define N_SAMP   32768
#define TWO_PI   6.283185307179586f
#define N_COEFFS 771
#define COEF_BLKS 144    // 16 row-tiles x 9 bin-tiles

typedef _Float16 half8 __attribute__((ext_vector_type(8)));
typedef float floatx4 __attribute__((ext_vector_type(4)));

// ============ Kernel 0: dense fused coef-GEMM (blocks 0..143) + basis =========
// coef GEMM replaces the CSC pipeline (measured ~83 us for ~0 work): each block
// computes 32 rows x 32 bins x 3 channels of C = relu(sel) @ items with the
// SAME ascending-k single-accumulator fp32 fmaf chain as the reference dense
// loop -> bit-identical coefs -> transcendentals fused -> pa={cos,sin,mag,D0}.
// Basis blocks (144..399) fold Hann+OLA into the fp16 B matrix:
//   chunks  0..17 : B'[k][n1]  = hann(n1)     * trig(k, n1)
//   chunks 18..35 : B''[k][n1] = hann(n1+256) * trig(k, n1+256)   (A shifted)
__global__ __launch_bounds__(256) void k_coef(const float* __restrict__ sel,
                                              const float* __restrict__ items,
                                              float4* __restrict__ pa,
                                              _Float16* __restrict__ Bt) {
    const int bid = blockIdx.x;
    const int tid = threadIdx.x;
    if (bid >= COEF_BLKS) {
        int n1 = bid - COEF_BLKS;            // output column 0..255
        for (int kk = tid; kk < 2 * KPAD; kk += 256) {
            int half = kk >= KPAD;
            int k    = kk - half * KPAD;
            int s    = n1 + half * 256;      // window position / sample index
            float w  = 0.5f - 0.5f * cosf(TWO_PI * (float)s / 511.f);
            float v  = 0.f;
            if (k < NBINS) {
                int r = (k * s) & 511;
                v = cosf(TWO_PI * (float)r * (1.f / 512.f)) * w;
            } else if (k < 2 * NBINS) {
                int r = ((k - NBINS) * s) & 511;
                v = -sinf(TWO_PI * (float)r * (1.f / 512.f)) * w;
            }
            size_t pos = ((size_t)((kk >> 5) * 4 + ((kk >> 3) & 3)) * NOUT + n1) * 8 + (kk & 7);
            Bt[pos] = (_Float16)v;
        }
        return;
    }
    // ---- coef GEMM tile: rows r0..r0+31, bins b0..b0+31, 3 channels ----
    __shared__ float sT[128 * 36];           // [k][32 rows] pad36 (16B-aligned rows)
    __shared__ float iT[128 * 96];           // [k][3 strips][32 cols]
    const int rt = bid / 9, bt = bid % 9;
    const int r0 = rt * 32, b0 = bt * 32;
    const int col = tid & 31;                // bin offset within tile
    const int rg  = tid >> 5;                // row group 0..7 (4 rows each)
    const int bin = b0 + col;

    float am[4] = {}, ap[4] = {}, as[4] = {};   // [row j] per channel
    for (int kc = 0; kc < 4; ++kc) {
        const int k0 = kc * 128;
        // stage sel chunk: thread (tr=tid>>3) row, (tid&7)*16 k-offset
        {
            int tr = tid >> 3, tk = (tid & 7) * 16;
            const float* sp = sel + (size_t)(r0 + tr) * 512 + k0 + tk;
            #pragma unroll
            for (int j = 0; j < 16; ++j) {
                float v = sp[j];
                sT[(tk + j) * 36 + tr] = v > 0.f ? v : 0.f;
            }
        }
        // stage items chunk: 3 strips of 32 cols
        {
            int kk = tid >> 5;               // 0..7
            #pragma unroll
            for (int k8 = 0; k8 < 128; k8 += 8) {
                int k = k8 + kk;
                const float* ip = items + (size_t)(k0 + k) * N_COEFFS;
                #pragma unroll
                for (int st = 0; st < 3; ++st) {
                    int c = st * NBINS + b0 + col;
                    iT[k * 96 + st * 32 + col] = (c < N_COEFFS) ? ip[c] : 0.f;
                }
            }
        }
        __syncthreads();
        for (int k = 0; k < 128; ++k) {      // ascending k -> bit-identical chain
            float4 sv = *(const float4*)&sT[k * 36 + rg * 4];
            float i0 = iT[k * 96 + col];
            float i1 = iT[k * 96 + 32 + col];
            float i2 = iT[k * 96 + 64 + col];
            am[0] = fmaf(sv.x, i0, am[0]); am[1] = fmaf(sv.y, i0, am[1]);
            am[2] = fmaf(sv.z, i0, am[2]); am[3] = fmaf(sv.w, i0, am[3]);
            ap[0] = fmaf(sv.x, i1, ap[0]); ap[1] = fmaf(sv.y, i1, ap[1]);
            ap[2] = fmaf(sv.z, i1, ap[2]); ap[3] = fmaf(sv.w, i1, ap[3]);
            as[0] = fmaf(sv.x, i2, as[0]); as[1] = fmaf(sv.y, i2, as[1]);
            as[2] = fmaf(sv.z, i2, as[2]); as[3] = fmaf(sv.w, i2, as[3]);
        }
        __syncthreads();
    }
    if (bin < NBINS) {
        float wgt = (bin == 0 || bin == 256) ? (1.f / 512.f) : (2.f / 512.f);
        #pragma unroll
        for (int j = 0; j < 4; ++j) {
            float sig_m = 1.f / (1.f + expf(-am[j]));
            float mag   = 0.5f + sig_m * 0.9999f * 0.5f;
            float ph    = tanhf(ap[j]) * 3.14159265358979323846f;
            float sph, cph;
            sincosf(ph, &sph, &cph);
            float st = 1.f / (1.f + expf(-as[j]));
            float D0 = 512.f * (st * wgt) * mag;
            pa[(size_t)(r0 + rg * 4 + j) * NBINS + bin] = make_float4(cph, sph, mag, D0);
        }
    }
}

// ============ Kernel 1: fused A-gen + MFMA(K=2x576) + norm + transposed store ==
// One block per row, 512 threads (8 waves = 2 wm x 4 wn), wave owns 64f x 64n.
// <=128 unified regs (64 AGPR acc + <=64 arch) -> 4 waves/SIMD, 2 blocks/CU.
// Epilogue stages 32-frame chunks through LDS (Asm reused) so each wave writes
// one FULL 1-KB frame row as float4 -> full-line streaming writes, no RMW.
__global__ __launch_bounds__(512, 4) void k_row(const float4* __restrict__ pag,
                                                const _Float16* __restrict__ basis,
                                                float* __restrict__ out) {
    __shared__ _Float16 Asm[PCH * 4096];   // 73728 B: 9 chunks x [f 128][32 swizzled]
    __shared__ float    par[NBINS * 4];    // {cos, sin, mag, D0} per bin
    __shared__ float    red[8];

    const int row  = blockIdx.x;
    const int t    = threadIdx.x;
    const int lane = t & 63;
    const int w    = t >> 6;
    const int wm   = w >> 2;            // frame-half 0..1 (64 frames each)
    const int wn   = w & 3;             // col-group 0..3 (64 output cols each)
    const int quad = lane >> 4;
    const int l16  = lane & 15;

    // ---------- load params ----------
    if (t < NBINS) {
        float4 P = pag[(size_t)row * NBINS + t];
        par[t * 4 + 0] = P.x; par[t * 4 + 1] = P.y;
        par[t * 4 + 2] = P.z; par[t * 4 + 3] = P.w;
    }
    __syncthreads();

    // ---------- A generation into Asm for one K-phase ----------
    auto agen = [&](int ph) {
        if (t < PCOLS) {
            int gc = ph * PCOLS + t;
            int bin; bool isCos;
            if (gc < NBINS)          { bin = gc;          isCos = true;  }
            else if (gc < 2 * NBINS) { bin = gc - NBINS;  isCos = false; }
            else                     { bin = 0;           isCos = true;  }
            float cph = par[bin * 4 + 0];
            float sph = par[bin * 4 + 1];
            float mag = par[bin * 4 + 2];
            float D   = par[bin * 4 + 3];
            if (gc >= 2 * NBINS) D = 0.f;
            float c = cph, s = sph;
            int ch = t >> 5, g = (t >> 3) & 3, o = t & 7;
            _Float16* base = &Asm[ch * 4096 + o];
            for (int f = 0; f < N_FRAMES; ++f) {
                float val = isCos ? D * c : D * s;
                base[f * 32 + ((g ^ ((f >> 1) & 3) ^ ((f >> 3) & 3)) << 3)] = (_Float16)val;
                D *= mag;
                float nc = fmaf(c, cph, -s * sph);
                float ns = fmaf(s, cph,  c * sph);
                c = nc; s = ns;
            }
        }
    };

    // B fragment base: element (chunk cb, plane quad, col u) at (cb*4+quad)*256*8 + u*8
    const _Float16* bbase = basis + ((size_t)quad * NOUT + wn * 64 + l16) * 8;

    floatx4 acc[4][4] = {};   // [mt][nt] — 64 AGPRs
    const half8 hz = {};

    for (int ph = 0; ph < 2; ++ph) {
        if (ph == 0) { agen(0); }
        else         { __syncthreads(); agen(1); }
        __syncthreads();
        for (int ks = 0; ks < PCH; ++ks) {
            const int cb0 = ph * PCH + ks;        // unshifted (h1) chunk
            const int cb1 = cb0 + 18;             // shifted (h2) chunk
            // ---- pass 1: unshifted A x B' ----
            {
                half8 av[4];
                #pragma unroll
                for (int mt = 0; mt < 4; ++mt) {
                    int m = wm * 64 + mt * 16 + l16;
                    av[mt] = *(const half8*)&Asm[ks * 4096 + m * 32 +
                              ((quad ^ ((m >> 1) & 3) ^ ((m >> 3) & 3)) << 3)];
                }
                #pragma unroll
                for (int nt = 0; nt < 4; ++nt) {
                    half8 bv = *(const half8*)(bbase + (size_t)cb0 * 8192 + nt * 128);
                    #pragma unroll
                    for (int mt = 0; mt < 4; ++mt)
                        acc[mt][nt] = __builtin_amdgcn_mfma_f32_16x16x32_f16(av[mt], bv, acc[mt][nt], 0, 0, 0);
                }
            }
            // ---- pass 2: frame-shifted A x B'' (reuses av registers) ----
            {
                half8 av[4];
                #pragma unroll
                for (int mt = 0; mt < 4; ++mt) {
                    int m  = wm * 64 + mt * 16 + l16;
                    int ms = m - 1; if (ms < 0) ms = 0;
                    av[mt] = *(const half8*)&Asm[ks * 4096 + ms * 32 +
                              ((quad ^ ((ms >> 1) & 3) ^ ((ms >> 3) & 3)) << 3)];
                }
                if (wm == 0 && l16 == 0) av[0] = hz;   // frame -1 contributes zero
                #pragma unroll
                for (int nt = 0; nt < 4; ++nt) {
                    half8 bv = *(const half8*)(bbase + (size_t)cb1 * 8192 + nt * 128);
                    #pragma unroll
                    for (int mt = 0; mt < 4; ++mt)
                        acc[mt][nt] = __builtin_amdgcn_mfma_f32_16x16x32_f16(av[mt], bv, acc[mt][nt], 0, 0, 0);
                }
            }
        }
    }

    // ---------- norm ----------
    float ssq = 0.f;
    #pragma unroll
    for (int mt = 0; mt < 4; ++mt)
        #pragma unroll
        for (int nt = 0; nt < 4; ++nt)
            #pragma unroll
            for (int rr = 0; rr < 4; ++rr)
                ssq = fmaf(acc[mt][nt][rr], acc[mt][nt][rr], ssq);
    #pragma unroll
    for (int off = 32; off > 0; off >>= 1) ssq += __shfl_down(ssq, off, 64);
    if (lane == 0) red[w] = ssq;
    __syncthreads();
    float tot = red[0] + red[1] + red[2] + red[3] + red[4] + red[5] + red[6] + red[7];
    float scale = 1.f / (sqrtf(tot) + 1e-8f);

    // ---------- coalesced store via LDS transpose (full-line writes) ----------
    float* stage = (float*)Asm;            // 32 frames x [260] = 33.3 KB (fits)
    float* orow  = out + (size_t)row * N_SAMP;
    __syncthreads();                       // all K-loop Asm reads complete
    for (int mt = 0; mt < 4; ++mt) {
        #pragma unroll
        for (int nt = 0; nt < 4; ++nt) {
            int n1 = wn * 64 + nt * 16 + l16;
            #pragma unroll
            for (int rr = 0; rr < 4; ++rr) {
                int fi = wm * 16 + quad * 4 + rr;         // 0..31
                stage[fi * 260 + n1] = acc[mt][nt][rr] * scale;
            }
        }
        __syncthreads();
        #pragma unroll
        for (int i = 0; i < 4; ++i) {
            int o4 = i * 512 + t;                          // float4 idx 0..2047
            int fi = o4 >> 6;                              // = i*8 + w
            int n1 = (o4 & 63) * 4;                        // = lane*4
            float4 v = *(const float4*)&stage[fi * 260 + n1];
            int f  = (fi >> 4) * 64 + mt * 16 + (fi & 15);
            *(float4*)&orow[f * 256 + n1] = v;             // 1 KB/wave, full lines
        }
        __syncthreads();
    }
}

extern "C" void kernel_launch(void* const* d_in, const int* in_sizes, int n_in,
                              void* d_out, int out_size, void* d_ws, size_t ws_size,
                              hipStream_t stream) {
    const float* sel   = (const float*)d_in[0];   // (8,16,4,512)
    const float* items = (const float*)d_in[1];   // (512,771)
    float* out = (float*)d_out;                   // (512, 32768)

    char* ws = (char*)d_ws;
    size_t off = 0;
    _Float16* basis = (_Float16*)(ws + off); off += (size_t)NCHUNKB * 4 * NOUT * 8 * 2; off = (off + 255) & ~255ull;
    float4* pa = (float4*)(ws + off); off += (size_t)N_ROWS * NBINS * 16; off = (off + 255) & ~255ull;

    k_coef<<<dim3(COEF_BLKS + NOUT), dim3(256), 0, stream>>>(sel, items, pa, basis);
    k_row<<<dim3(N_ROWS), dim3(512), 0, stream>>>(pa, basis, out);
}

// Round 9
// 185.112 us; speedup vs baseline: 1.1359x; 1.1359x over previous
//
#include <hip/hip_runtime.h>
#include <math.h>

#define N_ROWS   512     // 8*16*4
#define NBINS    257
#define KPAD     576     // padded K per window-half (18*32)
#define NCHUNKB  36      // B K-chunks: 18 unshifted (h1) + 18 shifted (h2)
#define PCH      9       // A-chunks resident per phase
#define PCOLS    288     // A columns generated per phase
#define NOUT     256     // output samples per frame (STEP)
#define N_FRAMES 128
#define N_SAMP   32768
#define TWO_PI   6.283185307179586f
#define N_COEFFS 771
#define COEF_BLKS 384    // 128 row-tiles (4 rows) x 3 channel strips

typedef _Float16 half8 __attribute__((ext_vector_type(8)));
typedef float floatx4 __attribute__((ext_vector_type(4)));

// ============ Kernel 0: coef GEMM (blocks 0..383) + windowed basis (384..639) ==
// coef: C = relu(sel) @ items, 4 rows x 257 cols of one channel strip per
// block. Thread t owns column strip*257+t: per k, ONE coalesced items load
// (257 consecutive floats across the block) + 4 LDS broadcast reads + 4
// independent fma chains. Ascending-k single-accumulator chain -> coefs
// BIT-IDENTICAL to the reference dense loop. 384 blocks x 5 waves = high
// occupancy (fixes R8's 144-block / 6% occupancy latency disaster).
// Basis blocks fold Hann+OLA into fp16 B:
//   chunks  0..17 : B'[k][n1]  = hann(n1)     * trig(k, n1)
//   chunks 18..35 : B''[k][n1] = hann(n1+256) * trig(k, n1+256)   (A shifted)
__global__ __launch_bounds__(320) void k_coef(const float* __restrict__ sel,
                                              const float* __restrict__ items,
                                              float* __restrict__ coef,
                                              _Float16* __restrict__ Bt) {
    const int bid = blockIdx.x;
    const int tid = threadIdx.x;
    if (bid >= COEF_BLKS) {
        int n1 = bid - COEF_BLKS;            // output column 0..255
        for (int kk = tid; kk < 2 * KPAD; kk += 320) {
            int half = kk >= KPAD;
            int k    = kk - half * KPAD;
            int s    = n1 + half * 256;      // window position / sample index
            float w  = 0.5f - 0.5f * cosf(TWO_PI * (float)s / 511.f);
            float v  = 0.f;
            if (k < NBINS) {
                int r = (k * s) & 511;
                v = cosf(TWO_PI * (float)r * (1.f / 512.f)) * w;
            } else if (k < 2 * NBINS) {
                int r = ((k - NBINS) * s) & 511;
                v = -sinf(TWO_PI * (float)r * (1.f / 512.f)) * w;
            }
            size_t pos = ((size_t)((kk >> 5) * 4 + ((kk >> 3) & 3)) * NOUT + n1) * 8 + (kk & 7);
            Bt[pos] = (_Float16)v;
        }
        return;
    }
    // ---- coef tile: rows r0..r0+3, channel strip, 257 columns ----
    const int rt = bid / 3, strip = bid % 3;
    const int r0 = rt * 4;
    __shared__ float s[2048];                // [4 rows][512 k], 8 KB
    for (int i = tid; i < 2048; i += 320) {
        float v = sel[(size_t)(r0 + (i >> 9)) * 512 + (i & 511)];
        s[i] = v > 0.f ? v : 0.f;
    }
    __syncthreads();
    if (tid <= 256) {
        const float* ip = items + strip * 257 + tid;
        float a0 = 0.f, a1 = 0.f, a2 = 0.f, a3 = 0.f;
        #pragma unroll 4
        for (int k = 0; k < 512; ++k) {      // ascending k -> bit-identical
            float iv = ip[(size_t)k * N_COEFFS];
            a0 = fmaf(s[k],        iv, a0);
            a1 = fmaf(s[512 + k],  iv, a1);
            a2 = fmaf(s[1024 + k], iv, a2);
            a3 = fmaf(s[1536 + k], iv, a3);
        }
        float* cp = coef + ((size_t)r0 * 3 + strip) * 257 + tid;
        cp[0]            = a0;
        cp[3 * 257]      = a1;
        cp[6 * 257]      = a2;
        cp[9 * 257]      = a3;
    }
}

// ============ Kernel 1: fused params + A-gen + MFMA(K=2x576) + norm ===========
// One block per row, 512 threads (8 waves = 2 wm x 4 wn), wave owns 64f x 64n.
// <=128 unified regs (64 AGPR acc + <=64 arch) -> 4 waves/SIMD, 2 blocks/CU.
// Prologue: 257 threads do the per-bin transcendentals from raw coefs.
// Store: direct scalar (R7 form — measured 92us; R8's LDS-transpose store with
// 12 extra barriers regressed to ~120us, reverted).
__global__ __launch_bounds__(512, 4) void k_row(const float* __restrict__ coefg,
                                                const _Float16* __restrict__ basis,
                                                float* __restrict__ out) {
    __shared__ _Float16 Asm[PCH * 4096];   // 73728 B: 9 chunks x [f 128][32 swizzled]
    __shared__ float    par[NBINS * 4];    // {cos, sin, mag, D0} per bin
    __shared__ float    red[8];

    const int row  = blockIdx.x;
    const int t    = threadIdx.x;
    const int lane = t & 63;
    const int w    = t >> 6;
    const int wm   = w >> 2;            // frame-half 0..1 (64 frames each)
    const int wn   = w & 3;             // col-group 0..3 (64 output cols each)
    const int quad = lane >> 4;
    const int l16  = lane & 15;

    // ---------- params: transcendentals from raw coefs ----------
    if (t < NBINS) {
        float cm = coefg[((size_t)row * 3 + 0) * 257 + t];
        float cp = coefg[((size_t)row * 3 + 1) * 257 + t];
        float cs = coefg[((size_t)row * 3 + 2) * 257 + t];
        float sig_m = 1.f / (1.f + expf(-cm));
        float mag   = 0.5f + sig_m * 0.9999f * 0.5f;
        float ph    = tanhf(cp) * 3.14159265358979323846f;
        float sph, cph;
        sincosf(ph, &sph, &cph);
        float st  = 1.f / (1.f + expf(-cs));
        float wgt = (t == 0 || t == 256) ? (1.f / 512.f) : (2.f / 512.f);
        par[t * 4 + 0] = cph;
        par[t * 4 + 1] = sph;
        par[t * 4 + 2] = mag;
        par[t * 4 + 3] = 512.f * (st * wgt) * mag;   // D0
    }
    __syncthreads();

    // ---------- A generation into Asm for one K-phase ----------
    auto agen = [&](int ph) {
        if (t < PCOLS) {
            int gc = ph * PCOLS + t;
            int bin; bool isCos;
            if (gc < NBINS)          { bin = gc;          isCos = true;  }
            else if (gc < 2 * NBINS) { bin = gc - NBINS;  isCos = false; }
            else                     { bin = 0;           isCos = true;  }
            float cph = par[bin * 4 + 0];
            float sph = par[bin * 4 + 1];
            float mag = par[bin * 4 + 2];
            float D   = par[bin * 4 + 3];
            if (gc >= 2 * NBINS) D = 0.f;
            float c = cph, s = sph;
            int ch = t >> 5, g = (t >> 3) & 3, o = t & 7;
            _Float16* base = &Asm[ch * 4096 + o];
            for (int f = 0; f < N_FRAMES; ++f) {
                float val = isCos ? D * c : D * s;
                base[f * 32 + ((g ^ ((f >> 1) & 3) ^ ((f >> 3) & 3)) << 3)] = (_Float16)val;
                D *= mag;
                float nc = fmaf(c, cph, -s * sph);
                float ns = fmaf(s, cph,  c * sph);
                c = nc; s = ns;
            }
        }
    };

    // B fragment base: element (chunk cb, plane quad, col u) at (cb*4+quad)*256*8 + u*8
    const _Float16* bbase = basis + ((size_t)quad * NOUT + wn * 64 + l16) * 8;

    floatx4 acc[4][4] = {};   // [mt][nt] — 64 AGPRs
    const half8 hz = {};

    for (int ph = 0; ph < 2; ++ph) {
        if (ph == 0) { agen(0); }
        else         { __syncthreads(); agen(1); }
        __syncthreads();
        for (int ks = 0; ks < PCH; ++ks) {
            const int cb0 = ph * PCH + ks;        // unshifted (h1) chunk
            const int cb1 = cb0 + 18;             // shifted (h2) chunk
            // ---- pass 1: unshifted A x B' ----
            {
                half8 av[4];
                #pragma unroll
                for (int mt = 0; mt < 4; ++mt) {
                    int m = wm * 64 + mt * 16 + l16;
                    av[mt] = *(const half8*)&Asm[ks * 4096 + m * 32 +
                              ((quad ^ ((m >> 1) & 3) ^ ((m >> 3) & 3)) << 3)];
                }
                #pragma unroll
                for (int nt = 0; nt < 4; ++nt) {
                    half8 bv = *(const half8*)(bbase + (size_t)cb0 * 8192 + nt * 128);
                    #pragma unroll
                    for (int mt = 0; mt < 4; ++mt)
                        acc[mt][nt] = __builtin_amdgcn_mfma_f32_16x16x32_f16(av[mt], bv, acc[mt][nt], 0, 0, 0);
                }
            }
            // ---- pass 2: frame-shifted A x B'' (reuses av registers) ----
            {
                half8 av[4];
                #pragma unroll
                for (int mt = 0; mt < 4; ++mt) {
                    int m  = wm * 64 + mt * 16 + l16;
                    int ms = m - 1; if (ms < 0) ms = 0;
                    av[mt] = *(const half8*)&Asm[ks * 4096 + ms * 32 +
                              ((quad ^ ((ms >> 1) & 3) ^ ((ms >> 3) & 3)) << 3)];
                }
                if (wm == 0 && l16 == 0) av[0] = hz;   // frame -1 contributes zero
                #pragma unroll
                for (int nt = 0; nt < 4; ++nt) {
                    half8 bv = *(const half8*)(bbase + (size_t)cb1 * 8192 + nt * 128);
                    #pragma unroll
                    for (int mt = 0; mt < 4; ++mt)
                        acc[mt][nt] = __builtin_amdgcn_mfma_f32_16x16x32_f16(av[mt], bv, acc[mt][nt], 0, 0, 0);
                }
            }
        }
    }

    // ---------- norm ----------
    float ssq = 0.f;
    #pragma unroll
    for (int mt = 0; mt < 4; ++mt)
        #pragma unroll
        for (int nt = 0; nt < 4; ++nt)
            #pragma unroll
            for (int rr = 0; rr < 4; ++rr)
                ssq = fmaf(acc[mt][nt][rr], acc[mt][nt][rr], ssq);
    #pragma unroll
    for (int off = 32; off > 0; off >>= 1) ssq += __shfl_down(ssq, off, 64);
    if (lane == 0) red[w] = ssq;
    __syncthreads();
    float tot = red[0] + red[1] + red[2] + red[3] + red[4] + red[5] + red[6] + red[7];
    float scale = 1.f / (sqrtf(tot) + 1e-8f);

    float* orow = out + (size_t)row * N_SAMP;
    #pragma unroll
    for (int mt = 0; mt < 4; ++mt) {
        #pragma unroll
        for (int nt = 0; nt < 4; ++nt) {
            int n1 = wn * 64 + nt * 16 + l16;
            #pragma unroll
            for (int rr = 0; rr < 4; ++rr) {
                int f = wm * 64 + mt * 16 + quad * 4 + rr;
                orow[f * 256 + n1] = acc[mt][nt][rr] * scale;
            }
        }
    }
}

extern "C" void kernel_launch(void* const* d_in, const int* in_sizes, int n_in,
                              void* d_out, int out_size, void* d_ws, size_t ws_size,
                              hipStream_t stream) {
    const float* sel   = (const float*)d_in[0];   // (8,16,4,512)
    const float* items = (const float*)d_in[1];   // (512,771)
    float* out = (float*)d_out;                   // (512, 32768)

    char* ws = (char*)d_ws;
    size_t off = 0;
    _Float16* basis = (_Float16*)(ws + off); off += (size_t)NCHUNKB * 4 * NOUT * 8 * 2; off = (off + 255) & ~255ull;
    float* coef = (float*)(ws + off); off += (size_t)N_ROWS * 3 * 257 * 4; off = (off + 255) & ~255ull;

    k_coef<<<dim3(COEF_BLKS + NOUT), dim3(320), 0, stream>>>(sel, items, coef, basis);
    k_row<<<dim3(N_ROWS), dim3(512), 0, stream>>>(coef, basis, out);
}